// Round 3
// baseline (1201.437 us; speedup 1.0000x reference)
//
#include <hip/hip_runtime.h>

#define MTOT 589824   // 4*384*384 pixels

typedef __attribute__((ext_vector_type(8))) short bf16x8;
typedef __attribute__((ext_vector_type(4))) float f32x4;
#define MFMA16 __builtin_amdgcn_mfma_f32_16x16x32_bf16

__device__ __forceinline__ unsigned short f2bf(float f) {
    union { float f; unsigned u; } x; x.f = f;
    unsigned r = x.u + 0x7FFFu + ((x.u >> 16) & 1u);
    return (unsigned short)(r >> 16);
}
__device__ __forceinline__ float bf2f(unsigned short h) {
    union { unsigned u; float f; } x; x.u = ((unsigned)h) << 16;
    return x.f;
}
__device__ __forceinline__ float2 bfpair(int v) {
    union { unsigned u; float f; } a, b;
    a.u = ((unsigned)v) << 16;
    b.u = ((unsigned)v) & 0xffff0000u;
    return make_float2(a.f, b.f);
}
// ln1_g is all-ones. bf16 ones -> ushort0 = 0x3F80 ; f32 ones -> ushort0 = 0x0000.
__device__ __forceinline__ int is_bf16(const void* ln1g) {
    return ((const unsigned short*)ln1g)[0] != 0;
}
__device__ __forceinline__ float ldp(const void* p, int i, int isbf) {
    return isbf ? bf2f(((const unsigned short*)p)[i]) : ((const float*)p)[i];
}
// load an MFMA A-fragment (8 consecutive channels) for one pixel from x
__device__ __forceinline__ bf16x8 load_afrag(const void* xg, long off, int isbf) {
    if (isbf) {
        return *(const bf16x8*)((const unsigned short*)xg + off);
    } else {
        const float* xf = (const float*)xg + off;
        float4 f0 = *(const float4*)xf;
        float4 f1 = *(const float4*)(xf + 4);
        bf16x8 r;
        r[0] = (short)f2bf(f0.x); r[1] = (short)f2bf(f0.y);
        r[2] = (short)f2bf(f0.z); r[3] = (short)f2bf(f0.w);
        r[4] = (short)f2bf(f1.x); r[5] = (short)f2bf(f1.y);
        r[6] = (short)f2bf(f1.z); r[7] = (short)f2bf(f1.w);
        return r;
    }
}

// ---------------------------------------------------------------- prep
// Wbase layout (ushort): Wqkv_t[192][64] | W1_t[128][64] | W2_t[64][128] | WF_t[64][64]
// P layout (f32): ln1g[64] ln1b[64] ff1b[128] ff2b[64] ln2g[64] ln2b[64] bnscale[64] bnbias[64]
__global__ void k_prep(const void* wq, const void* wk, const void* wv,
                       const void* ln1g, const void* ln1b,
                       const void* ff1w, const void* ff1b,
                       const void* ff2w, const void* ff2b,
                       const void* ln2g, const void* ln2b,
                       const void* wfuse, const void* bng, const void* bnb,
                       const void* bnm, const void* bnv,
                       unsigned short* Wbase, float* P) {
    const int isbf = is_bf16(ln1g);
    const int tid = blockIdx.x * blockDim.x + threadIdx.x;
    const int stride = gridDim.x * blockDim.x;
    unsigned short* Wqkv = Wbase;
    unsigned short* W1 = Wbase + 12288;
    unsigned short* W2 = W1 + 8192;
    unsigned short* WF = W2 + 8192;
    for (int i = tid; i < 12288; i += stride) {
        int n = i >> 6, k = i & 63;
        float v;
        if (n < 64)        v = ldp(wq, k*64 + n, isbf) * 0.25f;   // fold 1/sqrt(16)
        else if (n < 128)  v = ldp(wk, k*64 + (n-64), isbf);
        else               v = ldp(wv, k*64 + (n-128), isbf);
        Wqkv[n*64 + k] = f2bf(v);
    }
    for (int i = tid; i < 8192; i += stride) {   // ff1_w [64][128] -> [128][64]
        int n = i >> 6, k = i & 63;
        W1[n*64 + k] = f2bf(ldp(ff1w, k*128 + n, isbf));
    }
    for (int i = tid; i < 8192; i += stride) {   // ff2_w [128][64] -> [64][128]
        int n = i >> 7, k = i & 127;
        W2[n*128 + k] = f2bf(ldp(ff2w, k*64 + n, isbf));
    }
    for (int i = tid; i < 4096; i += stride) {   // w_fuse [64][64] -> [64][64]^T
        int n = i >> 6, k = i & 63;
        WF[n*64 + k] = f2bf(ldp(wfuse, k*64 + n, isbf));
    }
    for (int i = tid; i < 64; i += stride) {
        P[i]       = ldp(ln1g, i, isbf);
        P[64+i]    = ldp(ln1b, i, isbf);
        P[256+i]   = ldp(ff2b, i, isbf);
        P[320+i]   = ldp(ln2g, i, isbf);
        P[384+i]   = ldp(ln2b, i, isbf);
        float sc   = ldp(bng, i, isbf) * rsqrtf(ldp(bnv, i, isbf) + 1e-3f);
        P[448+i]   = sc;
        P[512+i]   = ldp(bnb, i, isbf) - ldp(bnm, i, isbf) * sc;
    }
    for (int i = tid; i < 128; i += stride) P[128+i] = ldp(ff1b, i, isbf);
}

// ---------------------------------------------------------------- fused front:
// per 16x16 tile: per head { MFMA q for inner px + k/v for 18x18 halo straight
// from global x -> LDS; per-thread 3x3 attention+softmax }, then residual + LN1,
// write y1 planar [MTOT][64]. qkv never touches HBM.
__global__ __launch_bounds__(256) void k_front(const void* __restrict__ xg,
                                               const void* __restrict__ ln1g,
                                               const unsigned short* __restrict__ Wqkv,
                                               const float* __restrict__ P,
                                               unsigned short* __restrict__ y1) {
    __shared__ unsigned short qh[256*20];    // inner-pixel q, one head
    __shared__ unsigned short kvh[324*36];   // halo k(0..15) v(16..31), one head
    const int t = threadIdx.x;
    const int bx = blockIdx.x % 24;
    const int by = (blockIdx.x / 24) % 24;
    const int bb = blockIdx.x / 576;
    const int isbf = is_bf16(ln1g);
    const int w = t >> 6, l = t & 63, lm = l & 15, q4 = l >> 4;
    const int tx = t & 15, ty = t >> 4;
    const long imgbase = (long)bb * 384 * 384;
    const bf16x8 zz = {0,0,0,0,0,0,0,0};

    float att[64];
    #pragma unroll
    for (int i = 0; i < 64; ++i) att[i] = 0.f;

    #pragma unroll
    for (int h = 0; h < 4; ++h) {
        // ---- MFMA: q (tiles 0..15) + halo k/v (tiles 16..87)
        for (int i = w; i < 88; i += 4) {
            long arow; int brow0; bool valid = true;
            if (i < 16) {
                arow = (imgbase + (long)(by*16 + i)*384 + bx*16 + lm) * 64;
                brow0 = h*16;                       // q rows of Wqkv_t
            } else {
                int j = i - 16, mtile = j >> 1, nt = j & 1;
                int hy = mtile >> 1, half = mtile & 1;
                int gy = by*16 + hy - 1, gx = bx*16 - 1 + half*2 + lm;
                valid = (gy >= 0) && (gy < 384) && (gx >= 0) && (gx < 384);
                int cgy = min(max(gy, 0), 383), cgx = min(max(gx, 0), 383);
                arow = (imgbase + (long)cgy*384 + cgx) * 64;
                brow0 = 64 + nt*64 + h*16;          // k or v rows
            }
            bf16x8 a0 = load_afrag(xg, arow + q4*8, isbf);
            bf16x8 a1 = load_afrag(xg, arow + 32 + q4*8, isbf);
            if (!valid) { a0 = zz; a1 = zz; }
            const unsigned short* wp = Wqkv + (brow0 + lm)*64 + q4*8;
            bf16x8 b0 = *(const bf16x8*)wp;
            bf16x8 b1 = *(const bf16x8*)(wp + 32);
            f32x4 acc = {0.f, 0.f, 0.f, 0.f};
            acc = MFMA16(a0, b0, acc, 0, 0, 0);
            acc = MFMA16(a1, b1, acc, 0, 0, 0);
            if (i < 16) {
                #pragma unroll
                for (int r = 0; r < 4; ++r)
                    qh[(i*16 + q4*4 + r)*20 + lm] = f2bf(acc[r]);
            } else {
                int j = i - 16, mtile = j >> 1, nt = j & 1;
                int hy = mtile >> 1, half = mtile & 1;
                #pragma unroll
                for (int r = 0; r < 4; ++r)
                    kvh[(hy*18 + half*2 + q4*4 + r)*36 + nt*16 + lm] = f2bf(acc[r]);
            }
        }
        __syncthreads();
        // ---- per-thread 3x3 attention for own pixel, this head
        float qv[16];
        {
            const int2* qp = (const int2*)&qh[t*20];
            #pragma unroll
            for (int j = 0; j < 4; ++j) {
                int2 u = qp[j];
                float2 pa = bfpair(u.x), pb = bfpair(u.y);
                qv[j*4+0] = pa.x; qv[j*4+1] = pa.y;
                qv[j*4+2] = pb.x; qv[j*4+3] = pb.y;
            }
        }
        float w9[9];
        #pragma unroll
        for (int e = 0; e < 9; ++e) {
            int dy = e / 3, dx = e - dy*3;
            const int2* kp = (const int2*)&kvh[((ty+dy)*18 + tx+dx)*36];
            float sacc = 0.f;
            #pragma unroll
            for (int j = 0; j < 4; ++j) {
                int2 kk = kp[j];
                float2 pa = bfpair(kk.x), pb = bfpair(kk.y);
                sacc += qv[j*4+0]*pa.x + qv[j*4+1]*pa.y
                      + qv[j*4+2]*pb.x + qv[j*4+3]*pb.y;
            }
            w9[e] = sacc;   // 1/sqrt(depth) folded into wq
        }
        float mx = w9[0];
        #pragma unroll
        for (int e = 1; e < 9; ++e) mx = fmaxf(mx, w9[e]);
        float den = 0.f;
        #pragma unroll
        for (int e = 0; e < 9; ++e) { w9[e] = __expf(w9[e] - mx); den += w9[e]; }
        const float inv = 1.f / den;
        #pragma unroll
        for (int e = 0; e < 9; ++e) {
            int dy = e / 3, dx = e - dy*3;
            const int2* vp = (const int2*)&kvh[((ty+dy)*18 + tx+dx)*36 + 16];
            const float wgt = w9[e] * inv;
            #pragma unroll
            for (int j = 0; j < 4; ++j) {
                int2 vv = vp[j];
                float2 pa = bfpair(vv.x), pb = bfpair(vv.y);
                att[h*16 + j*4+0] += wgt*pa.x;
                att[h*16 + j*4+1] += wgt*pa.y;
                att[h*16 + j*4+2] += wgt*pb.x;
                att[h*16 + j*4+3] += wgt*pb.y;
            }
        }
        __syncthreads();
    }
    // ---- residual + LN1 -> y1 (planar)
    const long pix = imgbase + (long)(by*16 + ty)*384 + bx*16 + tx;
    if (isbf) {
        const int4* xp = (const int4*)((const unsigned short*)xg + pix*64);
        #pragma unroll
        for (int j = 0; j < 8; ++j) {
            int4 u = xp[j];
            float2 pa = bfpair(u.x), pb = bfpair(u.y), pc = bfpair(u.z), pd = bfpair(u.w);
            att[j*8+0] += pa.x; att[j*8+1] += pa.y;
            att[j*8+2] += pb.x; att[j*8+3] += pb.y;
            att[j*8+4] += pc.x; att[j*8+5] += pc.y;
            att[j*8+6] += pd.x; att[j*8+7] += pd.y;
        }
    } else {
        const float4* xp = (const float4*)((const float*)xg + pix*64);
        #pragma unroll
        for (int j = 0; j < 16; ++j) {
            float4 f = xp[j];
            att[j*4+0] += f.x; att[j*4+1] += f.y;
            att[j*4+2] += f.z; att[j*4+3] += f.w;
        }
    }
    float s = 0.f, ss = 0.f;
    #pragma unroll
    for (int c = 0; c < 64; ++c) { s += att[c]; ss += att[c]*att[c]; }
    const float mean = s * (1.f/64.f);
    const float var  = ss * (1.f/64.f) - mean*mean;
    const float rs   = rsqrtf(var + 1e-3f);
    unsigned short* yp = y1 + pix*64;
    #pragma unroll
    for (int j = 0; j < 8; ++j) {
        unsigned v01 = (unsigned)f2bf((att[j*8+0]-mean)*rs*P[j*8+0] + P[64+j*8+0])
                     | ((unsigned)f2bf((att[j*8+1]-mean)*rs*P[j*8+1] + P[64+j*8+1]) << 16);
        unsigned v23 = (unsigned)f2bf((att[j*8+2]-mean)*rs*P[j*8+2] + P[64+j*8+2])
                     | ((unsigned)f2bf((att[j*8+3]-mean)*rs*P[j*8+3] + P[64+j*8+3]) << 16);
        unsigned v45 = (unsigned)f2bf((att[j*8+4]-mean)*rs*P[j*8+4] + P[64+j*8+4])
                     | ((unsigned)f2bf((att[j*8+5]-mean)*rs*P[j*8+5] + P[64+j*8+5]) << 16);
        unsigned v67 = (unsigned)f2bf((att[j*8+6]-mean)*rs*P[j*8+6] + P[64+j*8+6])
                     | ((unsigned)f2bf((att[j*8+7]-mean)*rs*P[j*8+7] + P[64+j*8+7]) << 16);
        int4 ov; ov.x = (int)v01; ov.y = (int)v23; ov.z = (int)v45; ov.w = (int)v67;
        *(int4*)(yp + j*8) = ov;
    }
}

// ---------------------------------------------------------------- fused tail:
// FFN1(relu) -> FFN2 + residual + LN2 -> fuse conv + BN + relu -> out
// reads planar y1 only; hh and y2 never touch HBM.
__global__ __launch_bounds__(256) void k_tail(const unsigned short* __restrict__ y1,
                                              const void* __restrict__ ln1g,
                                              const unsigned short* __restrict__ W1,
                                              const unsigned short* __restrict__ W2,
                                              const unsigned short* __restrict__ WF,
                                              const float* __restrict__ P,
                                              void* __restrict__ outg) {
    __shared__ unsigned short lA[64*72];      // y1 tile, later y2 tile
    __shared__ unsigned short hbuf[64*136];   // hh tile, later output staging
    const int t = threadIdx.x;
    const long m0 = (long)blockIdx.x * 64;
    #pragma unroll
    for (int j = 0; j < 2; ++j) {
        int e = (j*256 + t)*8, r = e >> 6, c = e & 63;
        *(int4*)&lA[r*72 + c] = *(const int4*)(y1 + m0*64 + e);
    }
    __syncthreads();
    const int w = t >> 6, l = t & 63, lm = l & 15, q4 = l >> 4;
    // ---- GEMM1: y1[64ch] x W1 -> hh[128ch], relu
    {
        const bf16x8 a0 = *(const bf16x8*)&lA[(w*16 + lm)*72 + q4*8];
        const bf16x8 a1 = *(const bf16x8*)&lA[(w*16 + lm)*72 + 32 + q4*8];
        #pragma unroll
        for (int nt = 0; nt < 8; ++nt) {
            const unsigned short* wp = W1 + (nt*16 + lm)*64 + q4*8;
            bf16x8 b0 = *(const bf16x8*)wp;
            bf16x8 b1 = *(const bf16x8*)(wp + 32);
            f32x4 acc = {0.f, 0.f, 0.f, 0.f};
            acc = MFMA16(a0, b0, acc, 0, 0, 0);
            acc = MFMA16(a1, b1, acc, 0, 0, 0);
            const float bias = P[128 + nt*16 + lm];
            #pragma unroll
            for (int r = 0; r < 4; ++r)
                hbuf[(w*16 + q4*4 + r)*136 + nt*16 + lm] = f2bf(fmaxf(acc[r] + bias, 0.f));
        }
    }
    __syncthreads();
    // ---- GEMM2: hh x W2 + ff2b + y1 residual, LN2 -> y2 (into lA)
    {
        bf16x8 a[4];
        #pragma unroll
        for (int kc = 0; kc < 4; ++kc)
            a[kc] = *(const bf16x8*)&hbuf[(w*16 + lm)*136 + kc*32 + q4*8];
        float v[4][4];
        #pragma unroll
        for (int nt = 0; nt < 4; ++nt) {
            f32x4 acc = {0.f, 0.f, 0.f, 0.f};
            #pragma unroll
            for (int kc = 0; kc < 4; ++kc) {
                bf16x8 b = *(const bf16x8*)(W2 + (nt*16 + lm)*128 + kc*32 + q4*8);
                acc = MFMA16(a[kc], b, acc, 0, 0, 0);
            }
            const int col = nt*16 + lm;
            const float bias = P[256 + col];
            #pragma unroll
            for (int r = 0; r < 4; ++r)
                v[nt][r] = acc[r] + bias + bf2f(lA[(w*16 + q4*4 + r)*72 + col]);
        }
        float s[4], ss[4];
        #pragma unroll
        for (int r = 0; r < 4; ++r) {
            s[r]  = v[0][r] + v[1][r] + v[2][r] + v[3][r];
            ss[r] = v[0][r]*v[0][r] + v[1][r]*v[1][r] + v[2][r]*v[2][r] + v[3][r]*v[3][r];
        }
        #pragma unroll
        for (int mk = 1; mk <= 8; mk <<= 1) {
            #pragma unroll
            for (int r = 0; r < 4; ++r) {
                s[r]  += __shfl_xor(s[r], mk);
                ss[r] += __shfl_xor(ss[r], mk);
            }
        }
        #pragma unroll
        for (int r = 0; r < 4; ++r) {
            const float mean = s[r] * (1.f/64.f);
            const float var  = ss[r] * (1.f/64.f) - mean*mean;
            const float rsv  = rsqrtf(var + 1e-3f);
            #pragma unroll
            for (int nt = 0; nt < 4; ++nt) {
                const int col = nt*16 + lm;
                lA[(w*16 + q4*4 + r)*72 + col] =
                    f2bf((v[nt][r] - mean)*rsv*P[320 + col] + P[384 + col]);
            }
        }
    }
    __syncthreads();
    // ---- GEMM3: y2 x WF, BN + relu -> out (stage in hbuf for coalesced stores)
    const int isbf = is_bf16(ln1g);
    {
        const bf16x8 a0 = *(const bf16x8*)&lA[(w*16 + lm)*72 + q4*8];
        const bf16x8 a1 = *(const bf16x8*)&lA[(w*16 + lm)*72 + 32 + q4*8];
        float* stf = (float*)hbuf + w*1024;                 // per-wave 4KB
        unsigned short* sth = hbuf + w*1024;                // per-wave 2KB
        #pragma unroll
        for (int nt = 0; nt < 4; ++nt) {
            const unsigned short* wp = WF + (nt*16 + lm)*64 + q4*8;
            bf16x8 b0 = *(const bf16x8*)wp;
            bf16x8 b1 = *(const bf16x8*)(wp + 32);
            f32x4 acc = {0.f, 0.f, 0.f, 0.f};
            acc = MFMA16(a0, b0, acc, 0, 0, 0);
            acc = MFMA16(a1, b1, acc, 0, 0, 0);
            const int col = nt*16 + lm;
            const float sc = P[448 + col], bi = P[512 + col];
            #pragma unroll
            for (int r = 0; r < 4; ++r) {
                float f = fmaxf(acc[r]*sc + bi, 0.f);
                if (isbf) sth[(q4*4 + r)*64 + col] = f2bf(f);
                else      stf[(q4*4 + r)*64 + col] = f;
            }
        }
    }
    __syncthreads();
    if (isbf) {
        const unsigned short* sth = hbuf + w*1024;
        unsigned short* orow = (unsigned short*)outg + m0*64;
        #pragma unroll
        for (int i = 0; i < 2; ++i) {
            int e = (i*64 + l)*8, r = e >> 6, c = e & 63;
            *(int4*)(orow + (long)(w*16 + r)*64 + c) = *(const int4*)&sth[e];
        }
    } else {
        const float* stf = (const float*)hbuf + w*1024;
        float* orow = (float*)outg + m0*64;
        #pragma unroll
        for (int i = 0; i < 4; ++i) {
            int e = (i*64 + l)*4, r = e >> 6, c = e & 63;
            *(float4*)(orow + (long)(w*16 + r)*64 + c) = *(const float4*)&stf[e];
        }
    }
}

// ---------------------------------------------------------------- launch
extern "C" void kernel_launch(void* const* d_in, const int* in_sizes, int n_in,
                              void* d_out, int out_size, void* d_ws, size_t ws_size,
                              hipStream_t stream) {
    const void* x     = d_in[0];
    const void* wq    = d_in[1];
    const void* wk    = d_in[2];
    const void* wv    = d_in[3];
    const void* ln1g  = d_in[4];
    const void* ln1b  = d_in[5];
    const void* ff1w  = d_in[6];
    const void* ff1b  = d_in[7];
    const void* ff2w  = d_in[8];
    const void* ff2b  = d_in[9];
    const void* ln2g  = d_in[10];
    const void* ln2b  = d_in[11];
    const void* wfuse = d_in[12];
    const void* bng   = d_in[13];
    const void* bnb   = d_in[14];
    const void* bnm   = d_in[15];
    const void* bnv   = d_in[16];

    // ws: y1 planar [MTOT][64] bf16 (75.5 MB), then weights+params (~68 KB)
    unsigned short* y1 = (unsigned short*)d_ws;
    unsigned short* Wbase = y1 + (size_t)MTOT * 64;
    float* P = (float*)(Wbase + 32768);

    k_prep <<<64, 256, 0, stream>>>(wq, wk, wv, ln1g, ln1b, ff1w, ff1b, ff2w, ff2b,
                                    ln2g, ln2b, wfuse, bng, bnb, bnm, bnv, Wbase, P);
    k_front<<<2304,    256, 0, stream>>>(x, ln1g, Wbase, P, y1);
    k_tail <<<MTOT/64, 256, 0, stream>>>(y1, ln1g,
                                         Wbase + 12288, Wbase + 20480, Wbase + 28672,
                                         P, d_out);
}

// Round 4
// 620.324 us; speedup vs baseline: 1.9368x; 1.9368x over previous
//
#include <hip/hip_runtime.h>

#define MTOT 589824   // 4*384*384 pixels

typedef __attribute__((ext_vector_type(8))) short bf16x8;
typedef __attribute__((ext_vector_type(4))) float f32x4;
#define MFMA16 __builtin_amdgcn_mfma_f32_16x16x32_bf16

__device__ __forceinline__ unsigned short f2bf(float f) {
    union { float f; unsigned u; } x; x.f = f;
    unsigned r = x.u + 0x7FFFu + ((x.u >> 16) & 1u);
    return (unsigned short)(r >> 16);
}
__device__ __forceinline__ float bf2f(unsigned short h) {
    union { unsigned u; float f; } x; x.u = ((unsigned)h) << 16;
    return x.f;
}
__device__ __forceinline__ float2 bfpair(int v) {
    union { unsigned u; float f; } a, b;
    a.u = ((unsigned)v) << 16;
    b.u = ((unsigned)v) & 0xffff0000u;
    return make_float2(a.f, b.f);
}
// ln1_g is all-ones. bf16 ones -> ushort0 = 0x3F80 ; f32 ones -> ushort0 = 0x0000.
__device__ __forceinline__ int is_bf16(const void* ln1g) {
    return ((const unsigned short*)ln1g)[0] != 0;
}
__device__ __forceinline__ float ldp(const void* p, int i, int isbf) {
    return isbf ? bf2f(((const unsigned short*)p)[i]) : ((const float*)p)[i];
}

// ---------------------------------------------------------------- prep
// Wbase (ushort): Wqkv_t[192][64] | W1_t[128][64] | W2_t[64][128] | WF_t[64][64]
// P (f32): ln1g[64] ln1b[64] ff1b[128] ff2b[64] ln2g[64] ln2b[64] bnscale[64] bnbias[64]
__global__ void k_prep(const void* wq, const void* wk, const void* wv,
                       const void* ln1g, const void* ln1b,
                       const void* ff1w, const void* ff1b,
                       const void* ff2w, const void* ff2b,
                       const void* ln2g, const void* ln2b,
                       const void* wfuse, const void* bng, const void* bnb,
                       const void* bnm, const void* bnv,
                       unsigned short* Wbase, float* P) {
    const int isbf = is_bf16(ln1g);
    const int tid = blockIdx.x * blockDim.x + threadIdx.x;
    const int stride = gridDim.x * blockDim.x;
    unsigned short* Wqkv = Wbase;
    unsigned short* W1 = Wbase + 12288;
    unsigned short* W2 = W1 + 8192;
    unsigned short* WF = W2 + 8192;
    for (int i = tid; i < 12288; i += stride) {
        int n = i >> 6, k = i & 63;
        float v;
        if (n < 64)        v = ldp(wq, k*64 + n, isbf) * 0.25f;   // fold 1/sqrt(16)
        else if (n < 128)  v = ldp(wk, k*64 + (n-64), isbf);
        else               v = ldp(wv, k*64 + (n-128), isbf);
        Wqkv[n*64 + k] = f2bf(v);
    }
    for (int i = tid; i < 8192; i += stride) {   // ff1_w [64][128] -> [128][64]
        int n = i >> 6, k = i & 63;
        W1[n*64 + k] = f2bf(ldp(ff1w, k*128 + n, isbf));
    }
    for (int i = tid; i < 8192; i += stride) {   // ff2_w [128][64] -> [64][128]
        int n = i >> 7, k = i & 127;
        W2[n*128 + k] = f2bf(ldp(ff2w, k*64 + n, isbf));
    }
    for (int i = tid; i < 4096; i += stride) {   // w_fuse [64][64] -> [64][64]^T
        int n = i >> 6, k = i & 63;
        WF[n*64 + k] = f2bf(ldp(wfuse, k*64 + n, isbf));
    }
    for (int i = tid; i < 64; i += stride) {
        P[i]       = ldp(ln1g, i, isbf);
        P[64+i]    = ldp(ln1b, i, isbf);
        P[256+i]   = ldp(ff2b, i, isbf);
        P[320+i]   = ldp(ln2g, i, isbf);
        P[384+i]   = ldp(ln2b, i, isbf);
        float sc   = ldp(bng, i, isbf) * rsqrtf(ldp(bnv, i, isbf) + 1e-3f);
        P[448+i]   = sc;
        P[512+i]   = ldp(bnb, i, isbf) - ldp(bnm, i, isbf) * sc;
    }
    for (int i = tid; i < 128; i += stride) P[128+i] = ldp(ff1b, i, isbf);
}

// ---------------------------------------------------------------- qkv GEMM
// outputs per-head planes: qp[4][MTOT][16] (scaled), kvp[4][MTOT][32] (k:0-15 v:16-31)
__global__ __launch_bounds__(256) void k_qkv(const void* __restrict__ xg,
                                             const void* __restrict__ ln1g,
                                             const unsigned short* __restrict__ Wqkv,
                                             unsigned short* __restrict__ qp,
                                             unsigned short* __restrict__ kvp) {
    __shared__ unsigned short lA[64*72];
    __shared__ unsigned short stg[64*200];
    const int t = threadIdx.x;
    const long m0 = (long)blockIdx.x * 64;
    if (is_bf16(ln1g)) {
        const unsigned short* xs = (const unsigned short*)xg + m0*64;
        #pragma unroll
        for (int j = 0; j < 2; ++j) {
            int e = (j*256 + t)*8, r = e >> 6, c = e & 63;
            *(int4*)&lA[r*72 + c] = *(const int4*)(xs + e);
        }
    } else {
        const float* xs = (const float*)xg + m0*64;
        #pragma unroll
        for (int j = 0; j < 4; ++j) {
            int e = (j*256 + t)*4, r = e >> 6, c = e & 63;
            float4 f = *(const float4*)(xs + e);
            ushort4 h;
            h.x = f2bf(f.x); h.y = f2bf(f.y); h.z = f2bf(f.z); h.w = f2bf(f.w);
            *(ushort4*)&lA[r*72 + c] = h;
        }
    }
    __syncthreads();
    const int w = t >> 6, l = t & 63, lm = l & 15, q4 = l >> 4;
    const bf16x8 a0 = *(const bf16x8*)&lA[(w*16 + lm)*72 + q4*8];
    const bf16x8 a1 = *(const bf16x8*)&lA[(w*16 + lm)*72 + 32 + q4*8];
    #pragma unroll
    for (int nt = 0; nt < 12; ++nt) {
        const unsigned short* wp = Wqkv + (nt*16 + lm)*64 + q4*8;
        bf16x8 b0 = *(const bf16x8*)wp;
        bf16x8 b1 = *(const bf16x8*)(wp + 32);
        f32x4 acc = {0.f, 0.f, 0.f, 0.f};
        acc = MFMA16(a0, b0, acc, 0, 0, 0);
        acc = MFMA16(a1, b1, acc, 0, 0, 0);
        #pragma unroll
        for (int r = 0; r < 4; ++r)
            stg[(w*16 + q4*4 + r)*200 + nt*16 + lm] = f2bf(acc[r]);
    }
    __syncthreads();
    const size_t P16 = (size_t)MTOT * 16, P32 = (size_t)MTOT * 32;
    // q planes: 512 int4
    #pragma unroll
    for (int j = 0; j < 2; ++j) {
        int idx = j*256 + t;
        int h = idx >> 7, rem = idx & 127, px = rem >> 1, part = rem & 1;
        *(int4*)(qp + (size_t)h*P16 + (m0 + px)*16 + part*8) =
            *(const int4*)&stg[px*200 + h*16 + part*8];
    }
    // kv planes: 1024 int4
    #pragma unroll
    for (int j = 0; j < 4; ++j) {
        int idx = j*256 + t;
        int h = idx >> 8, rem = idx & 255, px = rem >> 2, part = rem & 3;
        int scol = (part < 2) ? (64 + h*16 + part*8) : (128 + h*16 + (part-2)*8);
        *(int4*)(kvp + (size_t)h*P32 + (m0 + px)*32 + part*8) =
            *(const int4*)&stg[px*200 + scol];
    }
}

// ---------------------------------------------------------------- attention
// one (16x16 tile, head) per block. Reads kvp halo + own q; writes raw attention
// output (16 ch) IN-PLACE over the q plane (own-pixel only -> race-free).
__global__ __launch_bounds__(256) void k_attn(unsigned short* __restrict__ qp,
                                              const unsigned short* __restrict__ kvp) {
    __shared__ unsigned short kvh[324*36];   // per halo px: k[0..15] v[16..31] pad4
    const int t = threadIdx.x;
    const int h = blockIdx.x & 3;
    const int tile = blockIdx.x >> 2;
    const int bx = tile % 24;
    const int by = (tile / 24) % 24;
    const int bb = tile / 576;
    const long imgbase = (long)bb * 384 * 384;
    const unsigned short* kvplane = kvp + (size_t)h * MTOT * 32;
    unsigned short* qplane = qp + (size_t)h * MTOT * 16;

    for (int i = t; i < 2592; i += 256) {    // 324 halo px * 8 int2-chunks
        int p = i >> 3, part = i & 7;
        int hy = p / 18, hx = p - hy*18;
        int gy = by*16 + hy - 1, gx = bx*16 + hx - 1;
        int2 val = {0, 0};
        if (gy >= 0 && gy < 384 && gx >= 0 && gx < 384)
            val = *(const int2*)(kvplane + (imgbase + (long)gy*384 + gx)*32 + part*4);
        *(int2*)&kvh[p*36 + part*4] = val;
    }
    __syncthreads();

    const int tx = t & 15, ty = t >> 4;
    const long pix = imgbase + (long)(by*16 + ty)*384 + bx*16 + tx;
    float qv[16];
    {
        const int4 qa = *(const int4*)(qplane + pix*16);
        const int4 qb = *(const int4*)(qplane + pix*16 + 8);
        float2 p0;
        p0 = bfpair(qa.x); qv[0]  = p0.x; qv[1]  = p0.y;
        p0 = bfpair(qa.y); qv[2]  = p0.x; qv[3]  = p0.y;
        p0 = bfpair(qa.z); qv[4]  = p0.x; qv[5]  = p0.y;
        p0 = bfpair(qa.w); qv[6]  = p0.x; qv[7]  = p0.y;
        p0 = bfpair(qb.x); qv[8]  = p0.x; qv[9]  = p0.y;
        p0 = bfpair(qb.y); qv[10] = p0.x; qv[11] = p0.y;
        p0 = bfpair(qb.z); qv[12] = p0.x; qv[13] = p0.y;
        p0 = bfpair(qb.w); qv[14] = p0.x; qv[15] = p0.y;
    }
    float w9[9];
    #pragma unroll
    for (int e = 0; e < 9; ++e) {
        int dy = e / 3, dx = e - dy*3;
        const int2* kp = (const int2*)&kvh[((ty+dy)*18 + tx+dx)*36];
        float sacc = 0.f;
        #pragma unroll
        for (int j = 0; j < 4; ++j) {
            int2 kk = kp[j];
            float2 pa = bfpair(kk.x), pb = bfpair(kk.y);
            sacc += qv[j*4+0]*pa.x + qv[j*4+1]*pa.y
                  + qv[j*4+2]*pb.x + qv[j*4+3]*pb.y;
        }
        w9[e] = sacc;   // 1/sqrt(depth) folded into wq
    }
    float mx = w9[0];
    #pragma unroll
    for (int e = 1; e < 9; ++e) mx = fmaxf(mx, w9[e]);
    float den = 0.f;
    #pragma unroll
    for (int e = 0; e < 9; ++e) { w9[e] = __expf(w9[e] - mx); den += w9[e]; }
    const float inv = 1.f / den;
    float att[16];
    #pragma unroll
    for (int i = 0; i < 16; ++i) att[i] = 0.f;
    #pragma unroll
    for (int e = 0; e < 9; ++e) {
        int dy = e / 3, dx = e - dy*3;
        const int2* vp = (const int2*)&kvh[((ty+dy)*18 + tx+dx)*36 + 16];
        const float wgt = w9[e] * inv;
        #pragma unroll
        for (int j = 0; j < 4; ++j) {
            int2 vv = vp[j];
            float2 pa = bfpair(vv.x), pb = bfpair(vv.y);
            att[j*4+0] += wgt*pa.x;
            att[j*4+1] += wgt*pa.y;
            att[j*4+2] += wgt*pb.x;
            att[j*4+3] += wgt*pb.y;
        }
    }
    // write att over own q (16 ch)
    int4 o0, o1;
    o0.x = (int)((unsigned)f2bf(att[0])  | ((unsigned)f2bf(att[1])  << 16));
    o0.y = (int)((unsigned)f2bf(att[2])  | ((unsigned)f2bf(att[3])  << 16));
    o0.z = (int)((unsigned)f2bf(att[4])  | ((unsigned)f2bf(att[5])  << 16));
    o0.w = (int)((unsigned)f2bf(att[6])  | ((unsigned)f2bf(att[7])  << 16));
    o1.x = (int)((unsigned)f2bf(att[8])  | ((unsigned)f2bf(att[9])  << 16));
    o1.y = (int)((unsigned)f2bf(att[10]) | ((unsigned)f2bf(att[11]) << 16));
    o1.z = (int)((unsigned)f2bf(att[12]) | ((unsigned)f2bf(att[13]) << 16));
    o1.w = (int)((unsigned)f2bf(att[14]) | ((unsigned)f2bf(att[15]) << 16));
    *(int4*)(qplane + pix*16)     = o0;
    *(int4*)(qplane + pix*16 + 8) = o1;
}

// ---------------------------------------------------------------- fused tail:
// residual + LN1 -> FFN1(relu) -> FFN2 + residual + LN2 -> fuse conv + BN + relu
__global__ __launch_bounds__(256) void k_tail(const unsigned short* __restrict__ attp,
                                              const void* __restrict__ xg,
                                              const void* __restrict__ ln1g,
                                              const unsigned short* __restrict__ W1,
                                              const unsigned short* __restrict__ W2,
                                              const unsigned short* __restrict__ WF,
                                              const float* __restrict__ P,
                                              void* __restrict__ outg) {
    __shared__ unsigned short lA[64*72];      // y1 tile, later y2 tile
    __shared__ unsigned short hbuf[64*136];   // hh tile, later output staging
    const int t = threadIdx.x;
    const long m0 = (long)blockIdx.x * 64;
    const int isbf = is_bf16(ln1g);
    const size_t P16 = (size_t)MTOT * 16;
    // stage att planes -> lA [px][h*16+ch]
    #pragma unroll
    for (int j = 0; j < 2; ++j) {
        int idx = j*256 + t;
        int h = idx >> 7, rem = idx & 127, px = rem >> 1, part = rem & 1;
        *(int4*)&lA[px*72 + h*16 + part*8] =
            *(const int4*)(attp + (size_t)h*P16 + (m0 + px)*16 + part*8);
    }
    __syncthreads();
    // residual + LN1 (4 lanes per pixel, 16 ch each)
    {
        const int px = t >> 2, qtr = t & 3;
        float v[16];
        const int2* ap = (const int2*)&lA[px*72 + qtr*16];
        #pragma unroll
        for (int j = 0; j < 4; ++j) {
            int2 u = ap[j];
            float2 pa = bfpair(u.x), pb = bfpair(u.y);
            v[j*4+0] = pa.x; v[j*4+1] = pa.y; v[j*4+2] = pb.x; v[j*4+3] = pb.y;
        }
        if (isbf) {
            const int4* xp = (const int4*)((const unsigned short*)xg + (m0 + px)*64 + qtr*16);
            #pragma unroll
            for (int j = 0; j < 2; ++j) {
                int4 u = xp[j];
                float2 pa = bfpair(u.x), pb = bfpair(u.y), pc = bfpair(u.z), pd = bfpair(u.w);
                v[j*8+0] += pa.x; v[j*8+1] += pa.y;
                v[j*8+2] += pb.x; v[j*8+3] += pb.y;
                v[j*8+4] += pc.x; v[j*8+5] += pc.y;
                v[j*8+6] += pd.x; v[j*8+7] += pd.y;
            }
        } else {
            const float4* xp = (const float4*)((const float*)xg + (m0 + px)*64 + qtr*16);
            #pragma unroll
            for (int j = 0; j < 4; ++j) {
                float4 f = xp[j];
                v[j*4+0] += f.x; v[j*4+1] += f.y; v[j*4+2] += f.z; v[j*4+3] += f.w;
            }
        }
        float s = 0.f, ss = 0.f;
        #pragma unroll
        for (int c = 0; c < 16; ++c) { s += v[c]; ss += v[c]*v[c]; }
        s  += __shfl_xor(s, 1);  ss += __shfl_xor(ss, 1);
        s  += __shfl_xor(s, 2);  ss += __shfl_xor(ss, 2);
        const float mean = s * (1.f/64.f);
        const float var  = ss * (1.f/64.f) - mean*mean;
        const float rs   = rsqrtf(var + 1e-3f);
        unsigned short* wp = &lA[px*72 + qtr*16];
        #pragma unroll
        for (int c = 0; c < 16; ++c)
            wp[c] = f2bf((v[c] - mean)*rs*P[qtr*16 + c] + P[64 + qtr*16 + c]);
    }
    __syncthreads();
    const int w = t >> 6, l = t & 63, lm = l & 15, q4 = l >> 4;
    // ---- GEMM1: y1[64ch] x W1 -> hh[128ch], relu
    {
        const bf16x8 a0 = *(const bf16x8*)&lA[(w*16 + lm)*72 + q4*8];
        const bf16x8 a1 = *(const bf16x8*)&lA[(w*16 + lm)*72 + 32 + q4*8];
        #pragma unroll
        for (int nt = 0; nt < 8; ++nt) {
            const unsigned short* wp = W1 + (nt*16 + lm)*64 + q4*8;
            bf16x8 b0 = *(const bf16x8*)wp;
            bf16x8 b1 = *(const bf16x8*)(wp + 32);
            f32x4 acc = {0.f, 0.f, 0.f, 0.f};
            acc = MFMA16(a0, b0, acc, 0, 0, 0);
            acc = MFMA16(a1, b1, acc, 0, 0, 0);
            const float bias = P[128 + nt*16 + lm];
            #pragma unroll
            for (int r = 0; r < 4; ++r)
                hbuf[(w*16 + q4*4 + r)*136 + nt*16 + lm] = f2bf(fmaxf(acc[r] + bias, 0.f));
        }
    }
    __syncthreads();
    // ---- GEMM2: hh x W2 + ff2b + y1 residual, LN2 -> y2 (into lA)
    {
        bf16x8 a[4];
        #pragma unroll
        for (int kc = 0; kc < 4; ++kc)
            a[kc] = *(const bf16x8*)&hbuf[(w*16 + lm)*136 + kc*32 + q4*8];
        float v[4][4];
        #pragma unroll
        for (int nt = 0; nt < 4; ++nt) {
            f32x4 acc = {0.f, 0.f, 0.f, 0.f};
            #pragma unroll
            for (int kc = 0; kc < 4; ++kc) {
                bf16x8 b = *(const bf16x8*)(W2 + (nt*16 + lm)*128 + kc*32 + q4*8);
                acc = MFMA16(a[kc], b, acc, 0, 0, 0);
            }
            const int col = nt*16 + lm;
            const float bias = P[256 + col];
            #pragma unroll
            for (int r = 0; r < 4; ++r)
                v[nt][r] = acc[r] + bias + bf2f(lA[(w*16 + q4*4 + r)*72 + col]);
        }
        float s[4], ss[4];
        #pragma unroll
        for (int r = 0; r < 4; ++r) {
            s[r]  = v[0][r] + v[1][r] + v[2][r] + v[3][r];
            ss[r] = v[0][r]*v[0][r] + v[1][r]*v[1][r] + v[2][r]*v[2][r] + v[3][r]*v[3][r];
        }
        #pragma unroll
        for (int mk = 1; mk <= 8; mk <<= 1) {
            #pragma unroll
            for (int r = 0; r < 4; ++r) {
                s[r]  += __shfl_xor(s[r], mk);
                ss[r] += __shfl_xor(ss[r], mk);
            }
        }
        __syncthreads();   // all lA (y1) reads done before overwrite
        #pragma unroll
        for (int r = 0; r < 4; ++r) {
            const float mean = s[r] * (1.f/64.f);
            const float var  = ss[r] * (1.f/64.f) - mean*mean;
            const float rsv  = rsqrtf(var + 1e-3f);
            #pragma unroll
            for (int nt = 0; nt < 4; ++nt) {
                const int col = nt*16 + lm;
                lA[(w*16 + q4*4 + r)*72 + col] =
                    f2bf((v[nt][r] - mean)*rsv*P[320 + col] + P[384 + col]);
            }
        }
    }
    __syncthreads();
    // ---- GEMM3: y2 x WF, BN + relu -> out (stage in hbuf for coalesced stores)
    {
        const bf16x8 a0 = *(const bf16x8*)&lA[(w*16 + lm)*72 + q4*8];
        const bf16x8 a1 = *(const bf16x8*)&lA[(w*16 + lm)*72 + 32 + q4*8];
        float* stf = (float*)hbuf + w*1024;                 // per-wave 4KB
        unsigned short* sth = hbuf + w*1024;                // per-wave 2KB
        #pragma unroll
        for (int nt = 0; nt < 4; ++nt) {
            const unsigned short* wp = WF + (nt*16 + lm)*64 + q4*8;
            bf16x8 b0 = *(const bf16x8*)wp;
            bf16x8 b1 = *(const bf16x8*)(wp + 32);
            f32x4 acc = {0.f, 0.f, 0.f, 0.f};
            acc = MFMA16(a0, b0, acc, 0, 0, 0);
            acc = MFMA16(a1, b1, acc, 0, 0, 0);
            const int col = nt*16 + lm;
            const float sc = P[448 + col], bi = P[512 + col];
            #pragma unroll
            for (int r = 0; r < 4; ++r) {
                float f = fmaxf(acc[r]*sc + bi, 0.f);
                if (isbf) sth[(q4*4 + r)*64 + col] = f2bf(f);
                else      stf[(q4*4 + r)*64 + col] = f;
            }
        }
    }
    __syncthreads();
    if (isbf) {
        const unsigned short* sth = hbuf + w*1024;
        unsigned short* orow = (unsigned short*)outg + m0*64;
        #pragma unroll
        for (int i = 0; i < 2; ++i) {
            int e = (i*64 + l)*8, r = e >> 6, c = e & 63;
            *(int4*)(orow + (long)(w*16 + r)*64 + c) = *(const int4*)&sth[e];
        }
    } else {
        const float* stf = (const float*)hbuf + w*1024;
        float* orow = (float*)outg + m0*64;
        #pragma unroll
        for (int i = 0; i < 4; ++i) {
            int e = (i*64 + l)*4, r = e >> 6, c = e & 63;
            *(float4*)(orow + (long)(w*16 + r)*64 + c) = *(const float4*)&stf[e];
        }
    }
}

// ---------------------------------------------------------------- launch
extern "C" void kernel_launch(void* const* d_in, const int* in_sizes, int n_in,
                              void* d_out, int out_size, void* d_ws, size_t ws_size,
                              hipStream_t stream) {
    const void* x     = d_in[0];
    const void* wq    = d_in[1];
    const void* wk    = d_in[2];
    const void* wv    = d_in[3];
    const void* ln1g  = d_in[4];
    const void* ln1b  = d_in[5];
    const void* ff1w  = d_in[6];
    const void* ff1b  = d_in[7];
    const void* ff2w  = d_in[8];
    const void* ff2b  = d_in[9];
    const void* ln2g  = d_in[10];
    const void* ln2b  = d_in[11];
    const void* wfuse = d_in[12];
    const void* bng   = d_in[13];
    const void* bnb   = d_in[14];
    const void* bnm   = d_in[15];
    const void* bnv   = d_in[16];

    // ws: qp[4][MTOT][16] (75.5 MB, reused as attention-output planes)
    //   | kvp[4][MTOT][32] (151 MB) | weights+params (~68 KB)
    unsigned short* qp  = (unsigned short*)d_ws;
    unsigned short* kvp = qp + (size_t)4 * MTOT * 16;
    unsigned short* Wbase = kvp + (size_t)4 * MTOT * 32;
    float* P = (float*)(Wbase + 32768);

    k_prep<<<64, 256, 0, stream>>>(wq, wk, wv, ln1g, ln1b, ff1w, ff1b, ff2w, ff2b,
                                   ln2g, ln2b, wfuse, bng, bnb, bnm, bnv, Wbase, P);
    k_qkv <<<MTOT/64, 256, 0, stream>>>(x, ln1g, Wbase, qp, kvp);
    k_attn<<<9216,    256, 0, stream>>>(qp, kvp);
    k_tail<<<MTOT/64, 256, 0, stream>>>(qp, x, ln1g,
                                        Wbase + 12288, Wbase + 20480, Wbase + 28672,
                                        P, d_out);
}